// Round 1
// baseline (888.862 us; speedup 1.0000x reference)
//
#include <hip/hip_runtime.h>

// ---------------------------------------------------------------------------
// SelfAttention: x[4,2048,2048] f32; wq,wk,wv,wo [2048,2048] f32 (nn.Linear,
// so y = x @ W.T).  Pipeline:
//   K0 cvt5:     f32->bf16 for x and all weights (into ws)
//   K1 qkv_gemm: Q = (x wq^T)*1/sqrt(128) -> [B,H,S,HD]; K likewise; V -> V^T [B,H,HD,S]
//   K2 attn:     causal flash attention per (head, 64-row q tile) -> attn [B,S,D] bf16
//   K3 out_gemm: attn @ wo^T -> d_out f32
// All matmuls: 16x16x32 bf16 MFMA, BT-GEMM (both operands row-major [*,K]),
// m97 structure: 128x128 tile, BK=32, global_load_lds width 16.
// ---------------------------------------------------------------------------

#define B_  4
#define S_  2048
#define D_  2048
#define H_  16
#define HD_ 128

typedef __bf16 bf16x8 __attribute__((ext_vector_type(8)));
typedef float  f32x4  __attribute__((ext_vector_type(4)));

// workspace offsets in ushort (bf16) elements
#define OFF_XB  0u          // x bf16          [8192][2048]
#define OFF_WQ  16777216u   // wq bf16         [2048][2048]
#define OFF_WK  20971520u
#define OFF_WV  25165824u
#define OFF_WO  29360128u
#define OFF_QB  33554432u   // Q bf16 scaled   [64][2048][128]
#define OFF_KB  50331648u   // K bf16          [64][2048][128]
#define OFF_VT  67108864u   // V^T bf16        [64][128][2048]
#define OFF_AT  83886080u   // attn out bf16   [8192][2048]
// total 100,663,296 ushort = 192 MiB

#define GLOAD_LDS16(gsrc, ldst)                                                   \
  __builtin_amdgcn_global_load_lds(                                               \
      (const __attribute__((address_space(1))) void*)(gsrc),                      \
      (__attribute__((address_space(3))) void*)(ldst), 16, 0, 0)

__device__ __forceinline__ unsigned short f2bfu(float f) {
  unsigned u = __float_as_uint(f);
  return (unsigned short)((u + 0x7fffu + ((u >> 16) & 1u)) >> 16);  // RNE
}
__device__ __forceinline__ float bfu2f(unsigned short u) {
  return __uint_as_float(((unsigned)u) << 16);
}

// ---------------------------------------------------------------------------
// K0: convert x + 4 weights to bf16
// ---------------------------------------------------------------------------
__global__ __launch_bounds__(256) void cvt5(const float* __restrict__ x,
                                            const float* __restrict__ wq,
                                            const float* __restrict__ wk,
                                            const float* __restrict__ wv,
                                            const float* __restrict__ wo,
                                            unsigned short* __restrict__ ws) {
  long i = (long)blockIdx.x * 256 + threadIdx.x;  // float4 index
  const float* srcf;
  unsigned short* dst;
  long j;
  if (i < 4194304L)      { srcf = x;  dst = ws + OFF_XB; j = i; }
  else if (i < 5242880L) { srcf = wq; dst = ws + OFF_WQ; j = i - 4194304L; }
  else if (i < 6291456L) { srcf = wk; dst = ws + OFF_WK; j = i - 5242880L; }
  else if (i < 7340032L) { srcf = wv; dst = ws + OFF_WV; j = i - 6291456L; }
  else                   { srcf = wo; dst = ws + OFF_WO; j = i - 7340032L; }
  float4 v = ((const float4*)srcf)[j];
  ushort4 o;
  o.x = f2bfu(v.x); o.y = f2bfu(v.y); o.z = f2bfu(v.z); o.w = f2bfu(v.w);
  ((ushort4*)dst)[j] = o;
}

// ---------------------------------------------------------------------------
// shared BT-GEMM mainloop: C[128,128] tile = A[rowBase..+128, :] * Bt[colBase..+128, :]^T
// 256 threads = 4 waves (2x2), each wave 64x64 = 4x4 frags of 16x16x32 MFMA.
// ---------------------------------------------------------------------------
__device__ __forceinline__ void gemm128(const unsigned short* __restrict__ A,
                                        const unsigned short* __restrict__ Bt,
                                        int rowBase, int colBase, int Kdim,
                                        f32x4 (&acc)[4][4]) {
  __shared__ __align__(16) unsigned short As[128 * 32];
  __shared__ __align__(16) unsigned short Bs[128 * 32];
  const int tid = threadIdx.x, w = tid >> 6, l = tid & 63;
  const int wm = w >> 1, wn = w & 1;
  const int c = l & 15, g = l >> 4;

#pragma unroll
  for (int m = 0; m < 4; m++)
#pragma unroll
    for (int n = 0; n < 4; n++) acc[m][n] = (f32x4){0.f, 0.f, 0.f, 0.f};

  for (int k0 = 0; k0 < Kdim; k0 += 32) {
    // stage A-tile [128][32] and B-tile [128][32] (8KB each), linear LDS.
    // seg = 1KB of LDS = 16 rows x 64B; lane l covers bytes [l*16, l*16+16).
#pragma unroll
    for (int rr = 0; rr < 2; rr++) {
      int seg = rr * 4 + w;
      int row = seg * 16 + (l >> 2);
      int cb  = (l & 3) * 8;  // col in elems
      GLOAD_LDS16(A  + (size_t)(rowBase + row) * Kdim + k0 + cb, As + seg * 512);
      GLOAD_LDS16(Bt + (size_t)(colBase + row) * Kdim + k0 + cb, Bs + seg * 512);
    }
    __syncthreads();
    bf16x8 af[4], bfr[4];
#pragma unroll
    for (int m = 0; m < 4; m++)
      af[m] = *(const bf16x8*)&As[(wm * 64 + m * 16 + c) * 32 + g * 8];
#pragma unroll
    for (int n = 0; n < 4; n++)
      bfr[n] = *(const bf16x8*)&Bs[(wn * 64 + n * 16 + c) * 32 + g * 8];
#pragma unroll
    for (int m = 0; m < 4; m++)
#pragma unroll
      for (int n = 0; n < 4; n++)
        acc[m][n] = __builtin_amdgcn_mfma_f32_16x16x32_bf16(af[m], bfr[n], acc[m][n], 0, 0, 0);
    __syncthreads();
  }
}

// ---------------------------------------------------------------------------
// K1: QKV projection.  grid (64 tile_m, 16 h, 3 mat)
// ---------------------------------------------------------------------------
__global__ __launch_bounds__(256) void qkv_gemm(const unsigned short* __restrict__ xb,
                                                const unsigned short* __restrict__ wqb,
                                                const unsigned short* __restrict__ wkb,
                                                const unsigned short* __restrict__ wvb,
                                                unsigned short* __restrict__ Qb,
                                                unsigned short* __restrict__ Kb,
                                                unsigned short* __restrict__ Vtb) {
  const int tid = threadIdx.x, w = tid >> 6, l = tid & 63;
  const int wm = w >> 1, wn = w & 1;
  const int c = l & 15, g = l >> 4;
  const int mat = blockIdx.z;
  const unsigned short* Bt = (mat == 0) ? wqb : (mat == 1) ? wkb : wvb;

  f32x4 acc[4][4];
  gemm128(xb, Bt, blockIdx.x * 128, blockIdx.y * 128, D_, acc);

  const int b = (blockIdx.x * 128) / S_;          // whole tile in one batch
  const int sBase = (blockIdx.x * 128) & (S_ - 1);
  const size_t head = (size_t)(b * H_ + blockIdx.y);

  if (mat < 2) {
    unsigned short* dst = (mat == 0 ? Qb : Kb) + head * S_ * HD_;
    const float scale = (mat == 0) ? 0.08838834764831845f : 1.0f;
#pragma unroll
    for (int m = 0; m < 4; m++)
#pragma unroll
      for (int n = 0; n < 4; n++) {
        int chd = wn * 64 + n * 16 + c;
#pragma unroll
        for (int r = 0; r < 4; r++) {
          int s = sBase + wm * 64 + m * 16 + g * 4 + r;
          dst[(size_t)s * HD_ + chd] = f2bfu(acc[m][n][r] * scale);
        }
      }
  } else {
#pragma unroll
    for (int m = 0; m < 4; m++)
#pragma unroll
      for (int n = 0; n < 4; n++) {
        int chd = wn * 64 + n * 16 + c;
        int s0  = sBase + wm * 64 + m * 16 + g * 4;
        ushort4 o;
        o.x = f2bfu(acc[m][n][0]); o.y = f2bfu(acc[m][n][1]);
        o.z = f2bfu(acc[m][n][2]); o.w = f2bfu(acc[m][n][3]);
        *(ushort4*)&Vtb[(head * HD_ + chd) * S_ + s0] = o;
      }
  }
}

// ---------------------------------------------------------------------------
// K2: causal flash attention.  grid (32 qtile, 64 bh); 4 waves x 16 q-rows.
// K/Vt/P LDS tiles XOR-swizzled (byte ^= (row&7)<<4); K/Vt via pre-swizzled
// global source + linear global_load_lds dest (both-sides rule).
// ---------------------------------------------------------------------------
__global__ __launch_bounds__(256) void attn(const unsigned short* __restrict__ Qb,
                                            const unsigned short* __restrict__ Kb,
                                            const unsigned short* __restrict__ Vtb,
                                            unsigned short* __restrict__ atb) {
  const int qt = blockIdx.x;   // 0..31
  const int bh = blockIdx.y;   // 0..63
  const int tid = threadIdx.x, w = tid >> 6, l = tid & 63;
  const int c = l & 15, g = l >> 4;
  const int q0 = qt * 64;

  __shared__ __align__(16) unsigned short Ks[64 * 128];   // 16KB, 256B rows, swizzled
  __shared__ __align__(16) unsigned short Vs[128 * 64];   // 16KB, 128B rows, swizzled
  __shared__ __align__(16) unsigned short Ps[4][16 * 64]; // 2KB/wave, 128B rows, swizzled

  const unsigned short* Qh = Qb  + (size_t)bh * S_ * HD_;
  const unsigned short* Kh = Kb  + (size_t)bh * S_ * HD_;
  const unsigned short* Vh = Vtb + (size_t)bh * HD_ * S_;

  // Q fragments held in registers (A-operand): row = q0 + w*16 + c
  bf16x8 qf[4];
  {
    int qrow = q0 + w * 16 + c;
#pragma unroll
    for (int kc = 0; kc < 4; kc++)
      qf[kc] = *(const bf16x8*)&Qh[(size_t)qrow * HD_ + kc * 32 + g * 8];
  }

  f32x4 on[8];
#pragma unroll
  for (int n2 = 0; n2 < 8; n2++) on[n2] = (f32x4){0.f, 0.f, 0.f, 0.f};
  float mrow[4] = {-INFINITY, -INFINITY, -INFINITY, -INFINITY};
  float lrow[4] = {0.f, 0.f, 0.f, 0.f};

  for (int kt = 0; kt <= qt; ++kt) {
    const unsigned short* Kt = Kh + (size_t)kt * 64 * HD_;
    // stage K-tile [64][128]: 16 segs of 1KB (4 rows of 256B each)
#pragma unroll
    for (int rr = 0; rr < 4; rr++) {
      int seg = rr * 4 + w;
      int row = seg * 4 + (l >> 4);
      int cbs = ((l & 15) * 16) ^ ((row & 7) << 4);  // pre-swizzled source byte
      GLOAD_LDS16((const char*)Kt + row * 256 + cbs, (char*)Ks + seg * 1024);
    }
    // stage Vt-tile [128][64]: 16 segs of 1KB (8 rows of 128B each)
#pragma unroll
    for (int rr = 0; rr < 4; rr++) {
      int seg = rr * 4 + w;
      int row = seg * 8 + (l >> 3);
      int cbs = ((l & 7) * 16) ^ ((row & 7) << 4);
      GLOAD_LDS16((const char*)Vh + (size_t)row * (S_ * 2) + kt * 128 + cbs,
                  (char*)Vs + seg * 1024);
    }
    __syncthreads();

    // QK^T: scores 16x64 per wave
    f32x4 sc[4];
#pragma unroll
    for (int n = 0; n < 4; n++) sc[n] = (f32x4){0.f, 0.f, 0.f, 0.f};
#pragma unroll
    for (int n = 0; n < 4; n++) {
      int row = n * 16 + c;
#pragma unroll
      for (int kc = 0; kc < 4; kc++) {
        bf16x8 kf = *(const bf16x8*)((const char*)Ks + row * 256 +
                                     ((kc * 64 + g * 16) ^ ((row & 7) << 4)));
        sc[n] = __builtin_amdgcn_mfma_f32_16x16x32_bf16(qf[kc], kf, sc[n], 0, 0, 0);
      }
    }
    if (kt == qt) {  // diagonal tile: causal mask
#pragma unroll
      for (int n = 0; n < 4; n++)
#pragma unroll
        for (int r = 0; r < 4; r++) {
          int kk = kt * 64 + n * 16 + c;
          int qg = q0 + w * 16 + g * 4 + r;
          if (kk > qg) sc[n][r] = -INFINITY;
        }
    }

    // online softmax (per row r; row = w*16 + g*4 + r; 16 lanes c share a row)
    float mt[4], mn[4], corr[4], rs[4];
#pragma unroll
    for (int r = 0; r < 4; r++) {
      mt[r] = fmaxf(fmaxf(sc[0][r], sc[1][r]), fmaxf(sc[2][r], sc[3][r]));
#pragma unroll
      for (int d = 1; d < 16; d <<= 1) mt[r] = fmaxf(mt[r], __shfl_xor(mt[r], d));
      mn[r]   = fmaxf(mrow[r], mt[r]);
      corr[r] = __expf(mrow[r] - mn[r]);
      mrow[r] = mn[r];
      rs[r]   = 0.f;
    }
#pragma unroll
    for (int n = 0; n < 4; n++)
#pragma unroll
      for (int r = 0; r < 4; r++) {
        float p = __expf(sc[n][r] - mn[r]);
        unsigned short u = f2bfu(p);
        rs[r] += bfu2f(u);  // sum the bf16-rounded P for consistency with PV
        int prow = g * 4 + r;
        int cbyte = ((n * 16 + c) * 2) ^ ((prow & 7) << 4);
        *(unsigned short*)((char*)Ps[w] + prow * 128 + cbyte) = u;
      }
#pragma unroll
    for (int r = 0; r < 4; r++) {
#pragma unroll
      for (int d = 1; d < 16; d <<= 1) rs[r] += __shfl_xor(rs[r], d);
      lrow[r] = lrow[r] * corr[r] + rs[r];
    }
#pragma unroll
    for (int n2 = 0; n2 < 8; n2++)
#pragma unroll
      for (int r = 0; r < 4; r++) on[n2][r] *= corr[r];

    // PV: out[16,128] += P[16,64] * Vt[128,64]^T   (wave-local P, no barrier)
#pragma unroll
    for (int s = 0; s < 2; s++) {
      bf16x8 pa = *(const bf16x8*)((const char*)Ps[w] + c * 128 +
                                   ((s * 64 + g * 16) ^ ((c & 7) << 4)));
#pragma unroll
      for (int n2 = 0; n2 < 8; n2++) {
        int vrow = n2 * 16 + c;
        bf16x8 vb = *(const bf16x8*)((const char*)Vs + vrow * 128 +
                                     ((s * 64 + g * 16) ^ ((vrow & 7) << 4)));
        on[n2] = __builtin_amdgcn_mfma_f32_16x16x32_bf16(pa, vb, on[n2], 0, 0, 0);
      }
    }
    __syncthreads();  // protect Ks/Vs before next stage
  }

  // epilogue: normalize and write attn out [B,S,D] bf16
  const int b = bh >> 4, h = bh & 15;
  float inv[4];
#pragma unroll
  for (int r = 0; r < 4; r++) inv[r] = 1.f / lrow[r];
#pragma unroll
  for (int n2 = 0; n2 < 8; n2++)
#pragma unroll
    for (int r = 0; r < 4; r++) {
      size_t srow = (size_t)(b * S_ + q0 + w * 16 + g * 4 + r);
      atb[srow * D_ + h * HD_ + n2 * 16 + c] = f2bfu(on[n2][r] * inv[r]);
    }
}

// ---------------------------------------------------------------------------
// K3: output projection -> f32.  grid (64 tile_m, 16 tile_n)
// ---------------------------------------------------------------------------
__global__ __launch_bounds__(256) void out_gemm(const unsigned short* __restrict__ atb,
                                                const unsigned short* __restrict__ wob,
                                                float* __restrict__ out) {
  const int tid = threadIdx.x, w = tid >> 6, l = tid & 63;
  const int wm = w >> 1, wn = w & 1;
  const int c = l & 15, g = l >> 4;

  f32x4 acc[4][4];
  gemm128(atb, wob, blockIdx.x * 128, blockIdx.y * 128, D_, acc);

#pragma unroll
  for (int m = 0; m < 4; m++)
#pragma unroll
    for (int n = 0; n < 4; n++) {
      int col = blockIdx.y * 128 + wn * 64 + n * 16 + c;
#pragma unroll
      for (int r = 0; r < 4; r++) {
        int row = blockIdx.x * 128 + wm * 64 + m * 16 + g * 4 + r;
        out[(size_t)row * D_ + col] = acc[m][n][r];
      }
    }
}

// ---------------------------------------------------------------------------
extern "C" void kernel_launch(void* const* d_in, const int* in_sizes, int n_in,
                              void* d_out, int out_size, void* d_ws, size_t ws_size,
                              hipStream_t stream) {
  const float* x  = (const float*)d_in[0];
  const float* wq = (const float*)d_in[1];
  const float* wk = (const float*)d_in[2];
  const float* wv = (const float*)d_in[3];
  const float* wo = (const float*)d_in[4];
  unsigned short* ws = (unsigned short*)d_ws;
  float* out = (float*)d_out;

  unsigned short* xb  = ws + OFF_XB;
  unsigned short* wqb = ws + OFF_WQ;
  unsigned short* wkb = ws + OFF_WK;
  unsigned short* wvb = ws + OFF_WV;
  unsigned short* wob = ws + OFF_WO;
  unsigned short* Qb  = ws + OFF_QB;
  unsigned short* Kb  = ws + OFF_KB;
  unsigned short* Vtb = ws + OFF_VT;
  unsigned short* atb = ws + OFF_AT;

  hipLaunchKernelGGL(cvt5, dim3(32768), dim3(256), 0, stream, x, wq, wk, wv, wo, ws);
  hipLaunchKernelGGL(qkv_gemm, dim3(64, 16, 3), dim3(256), 0, stream,
                     xb, wqb, wkb, wvb, Qb, Kb, Vtb);
  hipLaunchKernelGGL(attn, dim3(32, 64), dim3(256), 0, stream, Qb, Kb, Vtb, atb);
  hipLaunchKernelGGL(out_gemm, dim3(64, 16), dim3(256), 0, stream, atb, wob, out);
}

// Round 3
// 776.297 us; speedup vs baseline: 1.1450x; 1.1450x over previous
//
#include <hip/hip_runtime.h>

// ---------------------------------------------------------------------------
// SelfAttention: x[4,2048,2048] f32; wq,wk,wv,wo [2048,2048] f32 (nn.Linear,
// so y = x @ W.T).  Pipeline:
//   K0 cvt5:     f32->bf16 for x and all weights (into ws)
//   K1 qkv_gemm: Q = (x wq^T)*1/sqrt(128) -> [B,H,S,HD]; K likewise; V -> V^T [B,H,HD,S]
//   K2 attn:     causal flash attention, 8-wave/128-row Q blocks, dbuf K/V
//   K3 out_gemm: attn @ wo^T -> d_out f32
// ---------------------------------------------------------------------------

#define B_  4
#define S_  2048
#define D_  2048
#define H_  16
#define HD_ 128

typedef __bf16 bf16x8 __attribute__((ext_vector_type(8)));
typedef float  f32x4  __attribute__((ext_vector_type(4)));

// workspace offsets in ushort (bf16) elements
#define OFF_XB  0u          // x bf16          [8192][2048]
#define OFF_WQ  16777216u   // wq bf16         [2048][2048]
#define OFF_WK  20971520u
#define OFF_WV  25165824u
#define OFF_WO  29360128u
#define OFF_QB  33554432u   // Q bf16 scaled   [64][2048][128]
#define OFF_KB  50331648u   // K bf16          [64][2048][128]
#define OFF_VT  67108864u   // V^T bf16        [64][128][2048]
#define OFF_AT  83886080u   // attn out bf16   [8192][2048]

#define GLOAD_LDS16(gsrc, ldst)                                                   \
  __builtin_amdgcn_global_load_lds(                                               \
      (const __attribute__((address_space(1))) void*)(gsrc),                      \
      (__attribute__((address_space(3))) void*)(ldst), 16, 0, 0)

__device__ __forceinline__ unsigned short f2bfu(float f) {
  unsigned u = __float_as_uint(f);
  return (unsigned short)((u + 0x7fffu + ((u >> 16) & 1u)) >> 16);  // RNE
}
__device__ __forceinline__ float bfu2f(unsigned short u) {
  return __uint_as_float(((unsigned)u) << 16);
}

// ---------------------------------------------------------------------------
// K0: convert x + 4 weights to bf16
// ---------------------------------------------------------------------------
__global__ __launch_bounds__(256) void cvt5(const float* __restrict__ x,
                                            const float* __restrict__ wq,
                                            const float* __restrict__ wk,
                                            const float* __restrict__ wv,
                                            const float* __restrict__ wo,
                                            unsigned short* __restrict__ ws) {
  long i = (long)blockIdx.x * 256 + threadIdx.x;  // float4 index
  const float* srcf;
  unsigned short* dst;
  long j;
  if (i < 4194304L)      { srcf = x;  dst = ws + OFF_XB; j = i; }
  else if (i < 5242880L) { srcf = wq; dst = ws + OFF_WQ; j = i - 4194304L; }
  else if (i < 6291456L) { srcf = wk; dst = ws + OFF_WK; j = i - 5242880L; }
  else if (i < 7340032L) { srcf = wv; dst = ws + OFF_WV; j = i - 6291456L; }
  else                   { srcf = wo; dst = ws + OFF_WO; j = i - 7340032L; }
  float4 v = ((const float4*)srcf)[j];
  ushort4 o;
  o.x = f2bfu(v.x); o.y = f2bfu(v.y); o.z = f2bfu(v.z); o.w = f2bfu(v.w);
  ((ushort4*)dst)[j] = o;
}

// ---------------------------------------------------------------------------
// shared BT-GEMM mainloop (m97 structure): C[128,128] = A[rB..+128,:]*Bt[cB..+128,:]^T
// ---------------------------------------------------------------------------
__device__ __forceinline__ void gemm128(const unsigned short* __restrict__ A,
                                        const unsigned short* __restrict__ Bt,
                                        int rowBase, int colBase, int Kdim,
                                        f32x4 (&acc)[4][4]) {
  __shared__ __align__(16) unsigned short As[128 * 32];
  __shared__ __align__(16) unsigned short Bs[128 * 32];
  const int tid = threadIdx.x, w = tid >> 6, l = tid & 63;
  const int wm = w >> 1, wn = w & 1;
  const int c = l & 15, g = l >> 4;

#pragma unroll
  for (int m = 0; m < 4; m++)
#pragma unroll
    for (int n = 0; n < 4; n++) acc[m][n] = (f32x4){0.f, 0.f, 0.f, 0.f};

  for (int k0 = 0; k0 < Kdim; k0 += 32) {
#pragma unroll
    for (int rr = 0; rr < 2; rr++) {
      int seg = rr * 4 + w;
      int row = seg * 16 + (l >> 2);
      int cb  = (l & 3) * 8;
      GLOAD_LDS16(A  + (size_t)(rowBase + row) * Kdim + k0 + cb, As + seg * 512);
      GLOAD_LDS16(Bt + (size_t)(colBase + row) * Kdim + k0 + cb, Bs + seg * 512);
    }
    __syncthreads();
    bf16x8 af[4], bfr[4];
#pragma unroll
    for (int m = 0; m < 4; m++)
      af[m] = *(const bf16x8*)&As[(wm * 64 + m * 16 + c) * 32 + g * 8];
#pragma unroll
    for (int n = 0; n < 4; n++)
      bfr[n] = *(const bf16x8*)&Bs[(wn * 64 + n * 16 + c) * 32 + g * 8];
#pragma unroll
    for (int m = 0; m < 4; m++)
#pragma unroll
      for (int n = 0; n < 4; n++)
        acc[m][n] = __builtin_amdgcn_mfma_f32_16x16x32_bf16(af[m], bfr[n], acc[m][n], 0, 0, 0);
    __syncthreads();
  }
}

// ---------------------------------------------------------------------------
// K1: QKV projection.  grid (64 tile_m, 16 h, 3 mat)
// ---------------------------------------------------------------------------
__global__ __launch_bounds__(256) void qkv_gemm(const unsigned short* __restrict__ xb,
                                                const unsigned short* __restrict__ wqb,
                                                const unsigned short* __restrict__ wkb,
                                                const unsigned short* __restrict__ wvb,
                                                unsigned short* __restrict__ Qb,
                                                unsigned short* __restrict__ Kb,
                                                unsigned short* __restrict__ Vtb) {
  const int tid = threadIdx.x, w = tid >> 6, l = tid & 63;
  const int wm = w >> 1, wn = w & 1;
  const int c = l & 15, g = l >> 4;
  const int mat = blockIdx.z;
  const unsigned short* Bt = (mat == 0) ? wqb : (mat == 1) ? wkb : wvb;

  f32x4 acc[4][4];
  gemm128(xb, Bt, blockIdx.x * 128, blockIdx.y * 128, D_, acc);

  const int b = (blockIdx.x * 128) / S_;
  const int sBase = (blockIdx.x * 128) & (S_ - 1);
  const size_t head = (size_t)(b * H_ + blockIdx.y);

  if (mat < 2) {
    unsigned short* dst = (mat == 0 ? Qb : Kb) + head * S_ * HD_;
    const float scale = (mat == 0) ? 0.08838834764831845f : 1.0f;
#pragma unroll
    for (int m = 0; m < 4; m++)
#pragma unroll
      for (int n = 0; n < 4; n++) {
        int chd = wn * 64 + n * 16 + c;
#pragma unroll
        for (int r = 0; r < 4; r++) {
          int s = sBase + wm * 64 + m * 16 + g * 4 + r;
          dst[(size_t)s * HD_ + chd] = f2bfu(acc[m][n][r] * scale);
        }
      }
  } else {
#pragma unroll
    for (int m = 0; m < 4; m++)
#pragma unroll
      for (int n = 0; n < 4; n++) {
        int chd = wn * 64 + n * 16 + c;
        int s0  = sBase + wm * 64 + m * 16 + g * 4;
        ushort4 o;
        o.x = f2bfu(acc[m][n][0]); o.y = f2bfu(acc[m][n][1]);
        o.z = f2bfu(acc[m][n][2]); o.w = f2bfu(acc[m][n][3]);
        *(ushort4*)&Vtb[(head * HD_ + chd) * S_ + s0] = o;
      }
  }
}

// ---------------------------------------------------------------------------
// K2: causal flash attention.  grid (16 qtile desc, 64 bh); 8 waves x 16 q-rows
// = 128-row Q tile.  K/V double-buffered (2-phase pattern: stage next tile's
// global_load_lds BEFORE computing current; one __syncthreads per tile).
// K/Vt/P LDS XOR-swizzled (byte ^= (row&7)<<4), pre-swizzled global source.
// ---------------------------------------------------------------------------
__global__ __launch_bounds__(512, 4) void attn(const unsigned short* __restrict__ Qb,
                                               const unsigned short* __restrict__ Kb,
                                               const unsigned short* __restrict__ Vtb,
                                               unsigned short* __restrict__ atb) {
  const int qt = (S_ / 128 - 1) - blockIdx.x;  // descending: longest blocks first
  const int bh = blockIdx.y;
  const int tid = threadIdx.x, w = tid >> 6, l = tid & 63;
  const int c = l & 15, g = l >> 4;
  const int q0 = qt * 128;
  const int nkt = 2 * qt + 2;  // K-tiles of 64 rows covering k <= q0+127

  __shared__ __align__(16) unsigned short Ks[2][64 * 128];   // 2x16KB swizzled
  __shared__ __align__(16) unsigned short Vs[2][128 * 64];   // 2x16KB swizzled
  __shared__ __align__(16) unsigned short Ps[8][16 * 64];    // 2KB/wave swizzled

  const unsigned short* Qh = Qb  + (size_t)bh * S_ * HD_;
  const unsigned short* Kh = Kb  + (size_t)bh * S_ * HD_;
  const unsigned short* Vh = Vtb + (size_t)bh * HD_ * S_;

  // Q fragments in registers: row = q0 + w*16 + c
  bf16x8 qf[4];
  {
    int qrow = q0 + w * 16 + c;
#pragma unroll
    for (int kc = 0; kc < 4; kc++)
      qf[kc] = *(const bf16x8*)&Qh[(size_t)qrow * HD_ + kc * 32 + g * 8];
  }

  f32x4 on[8];
#pragma unroll
  for (int n2 = 0; n2 < 8; n2++) on[n2] = (f32x4){0.f, 0.f, 0.f, 0.f};
  float mrow[4] = {-INFINITY, -INFINITY, -INFINITY, -INFINITY};
  float lrow[4] = {0.f, 0.f, 0.f, 0.f};

  // stage tile kt into buf: 8 waves x (2 K-segs + 2 V-segs) of 1KB each
  auto STAGE = [&](int buf, int kt) {
    const char* Kt = (const char*)(Kh + (size_t)kt * 64 * HD_);
#pragma unroll
    for (int rr = 0; rr < 2; rr++) {
      int seg = rr * 8 + w;
      {
        int row = seg * 4 + (l >> 4);
        int cbs = ((l & 15) * 16) ^ ((row & 7) << 4);
        GLOAD_LDS16(Kt + row * 256 + cbs, (char*)Ks[buf] + seg * 1024);
      }
      {
        int row = seg * 8 + (l >> 3);
        int cbs = ((l & 7) * 16) ^ ((row & 7) << 4);
        GLOAD_LDS16((const char*)Vh + (size_t)row * (S_ * 2) + kt * 128 + cbs,
                    (char*)Vs[buf] + seg * 1024);
      }
    }
  };

  STAGE(0, 0);
  __syncthreads();  // drain prologue loads (vmcnt+barrier)

  int cur = 0;
  for (int kt = 0; kt < nkt; ++kt) {
    if (kt + 1 < nkt) STAGE(cur ^ 1, kt + 1);  // loads fly under compute

    if (kt * 64 <= q0 + w * 16 + 15) {  // wave has at least one unmasked row
      // QK^T: scores 16x64
      f32x4 sc[4];
#pragma unroll
      for (int n = 0; n < 4; n++) sc[n] = (f32x4){0.f, 0.f, 0.f, 0.f};
      const char* KsB = (const char*)Ks[cur];
      __builtin_amdgcn_s_setprio(1);
#pragma unroll
      for (int n = 0; n < 4; n++) {
        int row = n * 16 + c;
#pragma unroll
        for (int kc = 0; kc < 4; kc++) {
          bf16x8 kf = *(const bf16x8*)(KsB + row * 256 +
                                       ((kc * 64 + g * 16) ^ ((row & 7) << 4)));
          sc[n] = __builtin_amdgcn_mfma_f32_16x16x32_bf16(qf[kc], kf, sc[n], 0, 0, 0);
        }
      }
      __builtin_amdgcn_s_setprio(0);

      if (kt * 64 + 63 > q0 + w * 16) {  // diagonal-overlap: causal mask
#pragma unroll
        for (int n = 0; n < 4; n++)
#pragma unroll
          for (int r = 0; r < 4; r++) {
            int kk = kt * 64 + n * 16 + c;
            int qg = q0 + w * 16 + g * 4 + r;
            if (kk > qg) sc[n][r] = -INFINITY;
          }
      }

      // online softmax
      float mt[4], mn[4], corr[4], rs[4];
#pragma unroll
      for (int r = 0; r < 4; r++) {
        mt[r] = fmaxf(fmaxf(sc[0][r], sc[1][r]), fmaxf(sc[2][r], sc[3][r]));
#pragma unroll
        for (int d = 1; d < 16; d <<= 1) mt[r] = fmaxf(mt[r], __shfl_xor(mt[r], d));
        mn[r]   = fmaxf(mrow[r], mt[r]);
        corr[r] = __expf(mrow[r] - mn[r]);
        mrow[r] = mn[r];
        rs[r]   = 0.f;
      }
#pragma unroll
      for (int n = 0; n < 4; n++)
#pragma unroll
        for (int r = 0; r < 4; r++) {
          float p = __expf(sc[n][r] - mn[r]);
          unsigned short u = f2bfu(p);
          rs[r] += bfu2f(u);
          int prow = g * 4 + r;
          int cbyte = ((n * 16 + c) * 2) ^ ((prow & 7) << 4);
          *(unsigned short*)((char*)Ps[w] + prow * 128 + cbyte) = u;
        }
#pragma unroll
      for (int r = 0; r < 4; r++) {
#pragma unroll
        for (int d = 1; d < 16; d <<= 1) rs[r] += __shfl_xor(rs[r], d);
        lrow[r] = lrow[r] * corr[r] + rs[r];
      }
#pragma unroll
      for (int n2 = 0; n2 < 8; n2++)
#pragma unroll
        for (int r = 0; r < 4; r++) on[n2][r] *= corr[r];

      // PV: out[16,128] += P[16,64] * Vt[128,64]^T  (wave-local P)
      const char* VsB = (const char*)Vs[cur];
#pragma unroll
      for (int s = 0; s < 2; s++) {
        bf16x8 pa = *(const bf16x8*)((const char*)Ps[w] + c * 128 +
                                     ((s * 64 + g * 16) ^ ((c & 7) << 4)));
        __builtin_amdgcn_s_setprio(1);
#pragma unroll
        for (int n2 = 0; n2 < 8; n2++) {
          int vrow = n2 * 16 + c;
          bf16x8 vb = *(const bf16x8*)(VsB + vrow * 128 +
                                       ((s * 64 + g * 16) ^ ((vrow & 7) << 4)));
          on[n2] = __builtin_amdgcn_mfma_f32_16x16x32_bf16(pa, vb, on[n2], 0, 0, 0);
        }
        __builtin_amdgcn_s_setprio(0);
      }
    }

    __syncthreads();  // drains this iter's prefetch loads + protects buffers
    cur ^= 1;
  }

  // epilogue: normalize and write attn out [B,S,D] bf16
  const int b = bh >> 4, h = bh & 15;
  float inv[4];
#pragma unroll
  for (int r = 0; r < 4; r++) inv[r] = 1.f / lrow[r];
#pragma unroll
  for (int n2 = 0; n2 < 8; n2++)
#pragma unroll
    for (int r = 0; r < 4; r++) {
      size_t srow = (size_t)(b * S_ + q0 + w * 16 + g * 4 + r);
      atb[srow * D_ + h * HD_ + n2 * 16 + c] = f2bfu(on[n2][r] * inv[r]);
    }
}

// ---------------------------------------------------------------------------
// K3: output projection -> f32.  grid (64 tile_m, 16 tile_n)
// ---------------------------------------------------------------------------
__global__ __launch_bounds__(256) void out_gemm(const unsigned short* __restrict__ atb,
                                                const unsigned short* __restrict__ wob,
                                                float* __restrict__ out) {
  const int tid = threadIdx.x, w = tid >> 6, l = tid & 63;
  const int wm = w >> 1, wn = w & 1;
  const int c = l & 15, g = l >> 4;

  f32x4 acc[4][4];
  gemm128(atb, wob, blockIdx.x * 128, blockIdx.y * 128, D_, acc);

#pragma unroll
  for (int m = 0; m < 4; m++)
#pragma unroll
    for (int n = 0; n < 4; n++) {
      int col = blockIdx.y * 128 + wn * 64 + n * 16 + c;
#pragma unroll
      for (int r = 0; r < 4; r++) {
        int row = blockIdx.x * 128 + wm * 64 + m * 16 + g * 4 + r;
        out[(size_t)row * D_ + col] = acc[m][n][r];
      }
    }
}

// ---------------------------------------------------------------------------
extern "C" void kernel_launch(void* const* d_in, const int* in_sizes, int n_in,
                              void* d_out, int out_size, void* d_ws, size_t ws_size,
                              hipStream_t stream) {
  const float* x  = (const float*)d_in[0];
  const float* wq = (const float*)d_in[1];
  const float* wk = (const float*)d_in[2];
  const float* wv = (const float*)d_in[3];
  const float* wo = (const float*)d_in[4];
  unsigned short* ws = (unsigned short*)d_ws;
  float* out = (float*)d_out;

  unsigned short* xb  = ws + OFF_XB;
  unsigned short* wqb = ws + OFF_WQ;
  unsigned short* wkb = ws + OFF_WK;
  unsigned short* wvb = ws + OFF_WV;
  unsigned short* wob = ws + OFF_WO;
  unsigned short* Qb  = ws + OFF_QB;
  unsigned short* Kb  = ws + OFF_KB;
  unsigned short* Vtb = ws + OFF_VT;
  unsigned short* atb = ws + OFF_AT;

  hipLaunchKernelGGL(cvt5, dim3(32768), dim3(256), 0, stream, x, wq, wk, wv, wo, ws);
  hipLaunchKernelGGL(qkv_gemm, dim3(64, 16, 3), dim3(256), 0, stream,
                     xb, wqb, wkb, wvb, Qb, Kb, Vtb);
  hipLaunchKernelGGL(attn, dim3(16, 64), dim3(512), 0, stream, Qb, Kb, Vtb, atb);
  hipLaunchKernelGGL(out_gemm, dim3(64, 16), dim3(256), 0, stream, atb, wob, out);
}

// Round 7
// 642.235 us; speedup vs baseline: 1.3840x; 1.2087x over previous
//
#include <hip/hip_runtime.h>

// ---------------------------------------------------------------------------
// SelfAttention: x[4,2048,2048] f32; wq,wk,wv,wo [2048,2048] f32 (y = x @ W.T)
//   K0 cvt5:     f32->bf16 for x and all weights
//   K1 qkv_gemm: 256x256-tile 8-phase GEMM -> Q,K [B,H,S,HD], V^T [B,H,HD,S]
//   K2 attn:     causal flash attention, 8-wave/128-row Q blocks, dbuf K/V
//   K3 out_gemm: 256x256-tile 8-phase GEMM -> d_out f32
// GEMM: T2 (XOR swizzle) + T3/T4 (8-phase counted vmcnt(6)) + T5 (setprio).
// ---------------------------------------------------------------------------

#define B_  4
#define S_  2048
#define D_  2048
#define H_  16
#define HD_ 128

typedef __bf16 bf16x8 __attribute__((ext_vector_type(8)));
typedef float  f32x4  __attribute__((ext_vector_type(4)));

#define OFF_XB  0u
#define OFF_WQ  16777216u
#define OFF_WK  20971520u
#define OFF_WV  25165824u
#define OFF_WO  29360128u
#define OFF_QB  33554432u
#define OFF_KB  50331648u
#define OFF_VT  67108864u
#define OFF_AT  83886080u

#define GLOAD_LDS16(gsrc, ldst)                                                   \
  __builtin_amdgcn_global_load_lds(                                               \
      (const __attribute__((address_space(1))) void*)(gsrc),                      \
      (__attribute__((address_space(3))) void*)(ldst), 16, 0, 0)

#define MFMA16(a, b, cacc) __builtin_amdgcn_mfma_f32_16x16x32_bf16(a, b, cacc, 0, 0, 0)

__device__ __forceinline__ unsigned short f2bfu(float f) {
  unsigned u = __float_as_uint(f);
  return (unsigned short)((u + 0x7fffu + ((u >> 16) & 1u)) >> 16);  // RNE
}
__device__ __forceinline__ float bfu2f(unsigned short u) {
  return __uint_as_float(((unsigned)u) << 16);
}

// ---------------------------------------------------------------------------
// K0: convert x + 4 weights to bf16
// ---------------------------------------------------------------------------
__global__ __launch_bounds__(256) void cvt5(const float* __restrict__ x,
                                            const float* __restrict__ wq,
                                            const float* __restrict__ wk,
                                            const float* __restrict__ wv,
                                            const float* __restrict__ wo,
                                            unsigned short* __restrict__ ws) {
  long i = (long)blockIdx.x * 256 + threadIdx.x;
  const float* srcf;
  unsigned short* dst;
  long j;
  if (i < 4194304L)      { srcf = x;  dst = ws + OFF_XB; j = i; }
  else if (i < 5242880L) { srcf = wq; dst = ws + OFF_WQ; j = i - 4194304L; }
  else if (i < 6291456L) { srcf = wk; dst = ws + OFF_WK; j = i - 5242880L; }
  else if (i < 7340032L) { srcf = wv; dst = ws + OFF_WV; j = i - 6291456L; }
  else                   { srcf = wo; dst = ws + OFF_WO; j = i - 7340032L; }
  float4 v = ((const float4*)srcf)[j];
  ushort4 o;
  o.x = f2bfu(v.x); o.y = f2bfu(v.y); o.z = f2bfu(v.z); o.w = f2bfu(v.w);
  ((ushort4*)dst)[j] = o;
}

// ---------------------------------------------------------------------------
// 256x256 8-phase BT-GEMM mainloop.  8 waves = 2(M) x 4(N); wave (wm,wn) owns
// m-frags at rows {32k+wm*16} (k=0..7) and n-frags at cols {64k'+wn*16}
// (k'=0..3).  A-halves = tile rows [0,128)/[128,256); B likewise.  Phase p of
// tile t computes one C-quadrant over BK=64:
//   p0:(m0-3 x n0-1)  p1:(m0-3 x n2-3)  p2:(m4-7 x n2-3)  p3:(m4-7 x n0-1)
// so each phase collectively reads ONE A-half and ONE B-half.  Staging runs
// ~1.75 tiles ahead: p0 stages A1(t+1); p1/p2/p3 stage A0/B0/B1(t+2).
// vmcnt(6) once per tile (3 half-tiles in flight); vmcnt(0) only at t=NT-2.
// LDS halves [128][64] bf16, 128B rows, chunk ^= row&7 swizzle (G4), staged
// via inverse-swizzled global source (both-sides rule).
// ---------------------------------------------------------------------------
__device__ __forceinline__ void stage_half(const unsigned short* __restrict__ g,
                                           int Kdim, int rowBase, int k0,
                                           unsigned short* lds, int w, int l) {
#pragma unroll
  for (int rr = 0; rr < 2; rr++) {
    int seg = w + rr * 8;                    // 16 segs of 1KB (8 rows x 128B)
    int row = seg * 8 + (l >> 3);            // row in half (row&7 == l>>3)
    int ccol = ((l & 7) ^ (l >> 3)) * 8;     // inverse-swizzled source chunk
    GLOAD_LDS16(g + (size_t)(rowBase + row) * Kdim + k0 + ccol, lds + seg * 512);
  }
}

__device__ __forceinline__ bf16x8 lds_frag(const unsigned short* half_, int row,
                                           int s, int g) {
  return *(const bf16x8*)((const char*)half_ + row * 128 +
                          ((s * 64 + g * 16) ^ ((row & 7) << 4)));
}

__device__ __forceinline__ void gemm256(const unsigned short* __restrict__ A,
                                        const unsigned short* __restrict__ Bt,
                                        int rowBase, int colBase, int Kdim,
                                        unsigned short* smem, f32x4 (&acc)[8][4]) {
  const int tid = threadIdx.x, w = tid >> 6, l = tid & 63;
  const int wm = w >> 2, wn = w & 3, c = l & 15, g = l >> 4;
  unsigned short* As = smem;            // [2 par][2 half][128*64]
  unsigned short* Bs = smem + 32768;
  const int NT = Kdim / 64;

#pragma unroll
  for (int i = 0; i < 8; i++)
#pragma unroll
    for (int j = 0; j < 4; j++) acc[i][j] = (f32x4){0.f, 0.f, 0.f, 0.f};

  // prologue: tile0 {A0,B0,B1,A1} + tile1 {A0,B0,B1}; vmcnt(6) -> tile0 landed
  stage_half(A,  Kdim, rowBase,       0,  As + 0 * 8192, w, l);
  stage_half(Bt, Kdim, colBase,       0,  Bs + 0 * 8192, w, l);
  stage_half(Bt, Kdim, colBase + 128, 0,  Bs + 1 * 8192, w, l);
  stage_half(A,  Kdim, rowBase + 128, 0,  As + 1 * 8192, w, l);
  stage_half(A,  Kdim, rowBase,       64, As + 2 * 8192, w, l);
  stage_half(Bt, Kdim, colBase,       64, Bs + 2 * 8192, w, l);
  stage_half(Bt, Kdim, colBase + 128, 64, Bs + 3 * 8192, w, l);
  asm volatile("s_waitcnt vmcnt(6)" ::: "memory");
  asm volatile("s_barrier" ::: "memory");

  bf16x8 aF[4][2], bF[4][2];

  for (int t = 0; t < NT; ++t) {
    const int par = t & 1;
    const unsigned short* A0h = As + (par * 2 + 0) * 8192;
    const unsigned short* A1h = As + (par * 2 + 1) * 8192;
    const unsigned short* B0h = Bs + (par * 2 + 0) * 8192;
    const unsigned short* B1h = Bs + (par * 2 + 1) * 8192;

    // ---- phase 0: ds A-lo(8) + B-lo(4); stage A1(t+1); mfma m0-3 x n0-1
#pragma unroll
    for (int m = 0; m < 4; m++) {
      int row = m * 32 + wm * 16 + c;
#pragma unroll
      for (int s = 0; s < 2; s++) aF[m][s] = lds_frag(A0h, row, s, g);
    }
#pragma unroll
    for (int n = 0; n < 2; n++) {
      int row = n * 64 + wn * 16 + c;
#pragma unroll
      for (int s = 0; s < 2; s++) bF[n][s] = lds_frag(B0h, row, s, g);
    }
    if (t + 1 < NT)
      stage_half(A, Kdim, rowBase + 128, (t + 1) * 64,
                 As + (((t + 1) & 1) * 2 + 1) * 8192, w, l);
    asm volatile("s_barrier" ::: "memory");
    __builtin_amdgcn_s_setprio(1);
#pragma unroll
    for (int m = 0; m < 4; m++)
#pragma unroll
      for (int n = 0; n < 2; n++)
#pragma unroll
        for (int s = 0; s < 2; s++) acc[m][n] = MFMA16(aF[m][s], bF[n][s], acc[m][n]);
    __builtin_amdgcn_s_setprio(0);
    asm volatile("s_barrier" ::: "memory");

    // ---- phase 1: ds B-hi(4); stage A0(t+2); mfma m0-3 x n2-3
#pragma unroll
    for (int n = 0; n < 2; n++) {
      int row = n * 64 + wn * 16 + c;
#pragma unroll
      for (int s = 0; s < 2; s++) bF[2 + n][s] = lds_frag(B1h, row, s, g);
    }
    if (t + 2 < NT)
      stage_half(A, Kdim, rowBase, (t + 2) * 64, As + (par * 2 + 0) * 8192, w, l);
    asm volatile("s_barrier" ::: "memory");
    __builtin_amdgcn_s_setprio(1);
#pragma unroll
    for (int m = 0; m < 4; m++)
#pragma unroll
      for (int n = 0; n < 2; n++)
#pragma unroll
        for (int s = 0; s < 2; s++)
          acc[m][2 + n] = MFMA16(aF[m][s], bF[2 + n][s], acc[m][2 + n]);
    __builtin_amdgcn_s_setprio(0);
    asm volatile("s_barrier" ::: "memory");

    // ---- phase 2: ds A-hi(8); stage B0(t+2); mfma m4-7 x n2-3
#pragma unroll
    for (int m = 0; m < 4; m++) {
      int row = m * 32 + wm * 16 + c;
#pragma unroll
      for (int s = 0; s < 2; s++) aF[m][s] = lds_frag(A1h, row, s, g);
    }
    if (t + 2 < NT)
      stage_half(Bt, Kdim, colBase, (t + 2) * 64, Bs + (par * 2 + 0) * 8192, w, l);
    asm volatile("s_barrier" ::: "memory");
    __builtin_amdgcn_s_setprio(1);
#pragma unroll
    for (int m = 0; m < 4; m++)
#pragma unroll
      for (int n = 0; n < 2; n++)
#pragma unroll
        for (int s = 0; s < 2; s++)
          acc[4 + m][2 + n] = MFMA16(aF[m][s], bF[2 + n][s], acc[4 + m][2 + n]);
    __builtin_amdgcn_s_setprio(0);
    asm volatile("s_barrier" ::: "memory");

    // ---- phase 3: no ds; stage B1(t+2); mfma m4-7 x n0-1; vmcnt; barrier
    if (t + 2 < NT)
      stage_half(Bt, Kdim, colBase + 128, (t + 2) * 64, Bs + (par * 2 + 1) * 8192, w, l);
    asm volatile("s_barrier" ::: "memory");
    __builtin_amdgcn_s_setprio(1);
#pragma unroll
    for (int m = 0; m < 4; m++)
#pragma unroll
      for (int n = 0; n < 2; n++)
#pragma unroll
        for (int s = 0; s < 2; s++)
          acc[4 + m][n] = MFMA16(aF[m][s], bF[n][s], acc[4 + m][n]);
    __builtin_amdgcn_s_setprio(0);
    if (t == NT - 2) asm volatile("s_waitcnt vmcnt(0)" ::: "memory");
    else             asm volatile("s_waitcnt vmcnt(6)" ::: "memory");
    asm volatile("s_barrier" ::: "memory");
  }
}

// ---------------------------------------------------------------------------
// K1: QKV projection.  grid (32 tile_m, 8 tile_n, 3 mat), 512 threads.
// ---------------------------------------------------------------------------
__global__ __launch_bounds__(512, 2) void qkv_gemm(const unsigned short* __restrict__ xb,
                                                   const unsigned short* __restrict__ wqb,
                                                   const unsigned short* __restrict__ wkb,
                                                   const unsigned short* __restrict__ wvb,
                                                   unsigned short* __restrict__ Qb,
                                                   unsigned short* __restrict__ Kb,
                                                   unsigned short* __restrict__ Vtb) {
  __shared__ __align__(16) unsigned short smem[65536];  // 128 KiB
  const int tid = threadIdx.x, w = tid >> 6, l = tid & 63;
  const int wm = w >> 2, wn = w & 3, c = l & 15, g = l >> 4;
  const int mat = blockIdx.z;
  const unsigned short* Bt = (mat == 0) ? wqb : (mat == 1) ? wkb : wvb;
  const int rowBase = blockIdx.x * 256, colBase = blockIdx.y * 256;

  f32x4 acc[8][4];
  gemm256(xb, Bt, rowBase, colBase, D_, smem, acc);

  const int b = rowBase / S_;
  const int sBase = rowBase & (S_ - 1);

  if (mat < 2) {
    unsigned short* dstb = (mat == 0 ? Qb : Kb);
    const float scale = (mat == 0) ? 0.08838834764831845f : 1.0f;
#pragma unroll
    for (int mk = 0; mk < 8; mk++)
#pragma unroll
      for (int nk = 0; nk < 4; nk++) {
        int colT = nk * 64 + wn * 16 + c;          // 0..255
        size_t head = (size_t)(b * H_ + blockIdx.y * 2 + (colT >> 7));
        int hd = colT & 127;
        unsigned short* dst = dstb + head * S_ * HD_;
#pragma unroll
        for (int r = 0; r < 4; r++) {
          int s = sBase + mk * 32 + wm * 16 + g * 4 + r;
          dst[(size_t)s * HD_ + hd] = f2bfu(acc[mk][nk][r] * scale);
        }
      }
  } else {
#pragma unroll
    for (int mk = 0; mk < 8; mk++)
#pragma unroll
      for (int nk = 0; nk < 4; nk++) {
        int colT = nk * 64 + wn * 16 + c;
        size_t head = (size_t)(b * H_ + blockIdx.y * 2 + (colT >> 7));
        int hd = colT & 127;
        int s0 = sBase + mk * 32 + wm * 16 + g * 4;
        ushort4 o;
        o.x = f2bfu(acc[mk][nk][0]); o.y = f2bfu(acc[mk][nk][1]);
        o.z = f2bfu(acc[mk][nk][2]); o.w = f2bfu(acc[mk][nk][3]);
        *(ushort4*)&Vtb[(head * HD_ + hd) * S_ + s0] = o;
      }
  }
}

// ---------------------------------------------------------------------------
// K2: causal flash attention (unchanged from round 1 rework).
// ---------------------------------------------------------------------------
__global__ __launch_bounds__(512, 4) void attn(const unsigned short* __restrict__ Qb,
                                               const unsigned short* __restrict__ Kb,
                                               const unsigned short* __restrict__ Vtb,
                                               unsigned short* __restrict__ atb) {
  const int qt = (S_ / 128 - 1) - blockIdx.x;
  const int bh = blockIdx.y;
  const int tid = threadIdx.x, w = tid >> 6, l = tid & 63;
  const int c = l & 15, g = l >> 4;
  const int q0 = qt * 128;
  const int nkt = 2 * qt + 2;

  __shared__ __align__(16) unsigned short Ks[2][64 * 128];
  __shared__ __align__(16) unsigned short Vs[2][128 * 64];
  __shared__ __align__(16) unsigned short Ps[8][16 * 64];

  const unsigned short* Qh = Qb  + (size_t)bh * S_ * HD_;
  const unsigned short* Kh = Kb  + (size_t)bh * S_ * HD_;
  const unsigned short* Vh = Vtb + (size_t)bh * HD_ * S_;

  bf16x8 qf[4];
  {
    int qrow = q0 + w * 16 + c;
#pragma unroll
    for (int kc = 0; kc < 4; kc++)
      qf[kc] = *(const bf16x8*)&Qh[(size_t)qrow * HD_ + kc * 32 + g * 8];
  }

  f32x4 on[8];
#pragma unroll
  for (int n2 = 0; n2 < 8; n2++) on[n2] = (f32x4){0.f, 0.f, 0.f, 0.f};
  float mrow[4] = {-INFINITY, -INFINITY, -INFINITY, -INFINITY};
  float lrow[4] = {0.f, 0.f, 0.f, 0.f};

  auto STAGE = [&](int buf, int kt) {
    const char* Kt = (const char*)(Kh + (size_t)kt * 64 * HD_);
#pragma unroll
    for (int rr = 0; rr < 2; rr++) {
      int seg = rr * 8 + w;
      {
        int row = seg * 4 + (l >> 4);
        int cbs = ((l & 15) * 16) ^ ((row & 7) << 4);
        GLOAD_LDS16(Kt + row * 256 + cbs, (char*)Ks[buf] + seg * 1024);
      }
      {
        int row = seg * 8 + (l >> 3);
        int cbs = ((l & 7) * 16) ^ ((row & 7) << 4);
        GLOAD_LDS16((const char*)Vh + (size_t)row * (S_ * 2) + kt * 128 + cbs,
                    (char*)Vs[buf] + seg * 1024);
      }
    }
  };

  STAGE(0, 0);
  __syncthreads();

  int cur = 0;
  for (int kt = 0; kt < nkt; ++kt) {
    if (kt + 1 < nkt) STAGE(cur ^ 1, kt + 1);

    if (kt * 64 <= q0 + w * 16 + 15) {
      f32x4 sc[4];
#pragma unroll
      for (int n = 0; n < 4; n++) sc[n] = (f32x4){0.f, 0.f, 0.f, 0.f};
      const char* KsB = (const char*)Ks[cur];
      __builtin_amdgcn_s_setprio(1);
#pragma unroll
      for (int n = 0; n < 4; n++) {
        int row = n * 16 + c;
#pragma unroll
        for (int kc = 0; kc < 4; kc++) {
          bf16x8 kf = *(const bf16x8*)(KsB + row * 256 +
                                       ((kc * 64 + g * 16) ^ ((row & 7) << 4)));
          sc[n] = MFMA16(qf[kc], kf, sc[n]);
        }
      }
      __builtin_amdgcn_s_setprio(0);

      if (kt * 64 + 63 > q0 + w * 16) {
#pragma unroll
        for (int n = 0; n < 4; n++)
#pragma unroll
          for (int r = 0; r < 4; r++) {
            int kk = kt * 64 + n * 16 + c;
            int qg = q0 + w * 16 + g * 4 + r;
            if (kk > qg) sc[n][r] = -INFINITY;
          }
      }

      float mt[4], mn[4], corr[4], rs[4];
#pragma unroll
      for (int r = 0; r < 4; r++) {
        mt[r] = fmaxf(fmaxf(sc[0][r], sc[1][r]), fmaxf(sc[2][r], sc[3][r]));
#pragma unroll
        for (int d = 1; d < 16; d <<= 1) mt[r] = fmaxf(mt[r], __shfl_xor(mt[r], d));
        mn[r]   = fmaxf(mrow[r], mt[r]);
        corr[r] = __expf(mrow[r] - mn[r]);
        mrow[r] = mn[r];
        rs[r]   = 0.f;
      }
#pragma unroll
      for (int n = 0; n < 4; n++)
#pragma unroll
        for (int r = 0; r < 4; r++) {
          float p = __expf(sc[n][r] - mn[r]);
          unsigned short u = f2bfu(p);
          rs[r] += bfu2f(u);
          int prow = g * 4 + r;
          int cbyte = ((n * 16 + c) * 2) ^ ((prow & 7) << 4);
          *(unsigned short*)((char*)Ps[w] + prow * 128 + cbyte) = u;
        }
#pragma unroll
      for (int r = 0; r < 4; r++) {
#pragma unroll
        for (int d = 1; d < 16; d <<= 1) rs[r] += __shfl_xor(rs[r], d);
        lrow[r] = lrow[r] * corr[r] + rs[r];
      }
#pragma unroll
      for (int n2 = 0; n2 < 8; n2++)
#pragma unroll
        for (int r = 0; r < 4; r++) on[n2][r] *= corr[r];

      const char* VsB = (const char*)Vs[cur];
#pragma unroll
      for (int s = 0; s < 2; s++) {
        bf16x8 pa = *(const bf16x8*)((const char*)Ps[w] + c * 128 +
                                     ((s * 64 + g * 16) ^ ((c & 7) << 4)));
        __builtin_amdgcn_s_setprio(1);
#pragma unroll
        for (int n2 = 0; n2 < 8; n2++) {
          int vrow = n2 * 16 + c;
          bf16x8 vb = *(const bf16x8*)(VsB + vrow * 128 +
                                       ((s * 64 + g * 16) ^ ((vrow & 7) << 4)));
          on[n2] = MFMA16(pa, vb, on[n2]);
        }
        __builtin_amdgcn_s_setprio(0);
      }
    }

    __syncthreads();
    cur ^= 1;
  }

  const int b = bh >> 4, h = bh & 15;
  float inv[4];
#pragma unroll
  for (int r = 0; r < 4; r++) inv[r] = 1.f / lrow[r];
#pragma unroll
  for (int n2 = 0; n2 < 8; n2++)
#pragma unroll
    for (int r = 0; r < 4; r++) {
      size_t srow = (size_t)(b * S_ + q0 + w * 16 + g * 4 + r);
      atb[srow * D_ + h * HD_ + n2 * 16 + c] = f2bfu(on[n2][r] * inv[r]);
    }
}

// ---------------------------------------------------------------------------
// K3: output projection -> f32.  grid (32 tile_m, 8 tile_n), 512 threads.
// ---------------------------------------------------------------------------
__global__ __launch_bounds__(512, 2) void out_gemm(const unsigned short* __restrict__ atb,
                                                   const unsigned short* __restrict__ wob,
                                                   float* __restrict__ out) {
  __shared__ __align__(16) unsigned short smem[65536];  // 128 KiB
  const int tid = threadIdx.x, w = tid >> 6, l = tid & 63;
  const int wm = w >> 2, wn = w & 3, c = l & 15, g = l >> 4;
  const int rowBase = blockIdx.x * 256, colBase = blockIdx.y * 256;

  f32x4 acc[8][4];
  gemm256(atb, wob, rowBase, colBase, D_, smem, acc);

#pragma unroll
  for (int mk = 0; mk < 8; mk++)
#pragma unroll
    for (int nk = 0; nk < 4; nk++) {
      int col = colBase + nk * 64 + wn * 16 + c;
#pragma unroll
      for (int r = 0; r < 4; r++) {
        int row = rowBase + mk * 32 + wm * 16 + g * 4 + r;
        out[(size_t)row * D_ + col] = acc[mk][nk][r];
      }
    }
}

// ---------------------------------------------------------------------------
extern "C" void kernel_launch(void* const* d_in, const int* in_sizes, int n_in,
                              void* d_out, int out_size, void* d_ws, size_t ws_size,
                              hipStream_t stream) {
  const float* x  = (const float*)d_in[0];
  const float* wq = (const float*)d_in[1];
  const float* wk = (const float*)d_in[2];
  const float* wv = (const float*)d_in[3];
  const float* wo = (const float*)d_in[4];
  unsigned short* ws = (unsigned short*)d_ws;
  float* out = (float*)d_out;

  unsigned short* xb  = ws + OFF_XB;
  unsigned short* wqb = ws + OFF_WQ;
  unsigned short* wkb = ws + OFF_WK;
  unsigned short* wvb = ws + OFF_WV;
  unsigned short* wob = ws + OFF_WO;
  unsigned short* Qb  = ws + OFF_QB;
  unsigned short* Kb  = ws + OFF_KB;
  unsigned short* Vtb = ws + OFF_VT;
  unsigned short* atb = ws + OFF_AT;

  hipLaunchKernelGGL(cvt5, dim3(32768), dim3(256), 0, stream, x, wq, wk, wv, wo, ws);
  hipLaunchKernelGGL(qkv_gemm, dim3(32, 8, 3), dim3(512), 0, stream,
                     xb, wqb, wkb, wvb, Qb, Kb, Vtb);
  hipLaunchKernelGGL(attn, dim3(16, 64), dim3(512), 0, stream, Qb, Kb, Vtb, atb);
  hipLaunchKernelGGL(out_gemm, dim3(32, 8), dim3(512), 0, stream, atb, wob, out);
}

// Round 8
// 554.352 us; speedup vs baseline: 1.6034x; 1.1585x over previous
//
#include <hip/hip_runtime.h>

// ---------------------------------------------------------------------------
// SelfAttention: x[4,2048,2048] f32; wq,wk,wv,wo [2048,2048] f32 (y = x @ W.T)
//   K0 cvt5:     f32->bf16 for x and all weights
//   K1 qkv_gemm: 256x256-tile 8-phase GEMM -> Q,K [B,H,S,HD], V^T [B,H,HD,S]
//                (Q pre-scaled by 1/sqrt(128)*log2(e): attn softmax in exp2 domain)
//   K2 attn:     causal flash attention, work-balanced grid (8,64): each block
//                handles q-tiles {15-i, i} = exactly 34 K-tiles; defer-max.
//   K3 out_gemm: 256x256-tile 8-phase GEMM -> d_out f32
// ---------------------------------------------------------------------------

#define B_  4
#define S_  2048
#define D_  2048
#define H_  16
#define HD_ 128

typedef __bf16 bf16x8 __attribute__((ext_vector_type(8)));
typedef float  f32x4  __attribute__((ext_vector_type(4)));

#define OFF_XB  0u
#define OFF_WQ  16777216u
#define OFF_WK  20971520u
#define OFF_WV  25165824u
#define OFF_WO  29360128u
#define OFF_QB  33554432u
#define OFF_KB  50331648u
#define OFF_VT  67108864u
#define OFF_AT  83886080u

#define GLOAD_LDS16(gsrc, ldst)                                                   \
  __builtin_amdgcn_global_load_lds(                                               \
      (const __attribute__((address_space(1))) void*)(gsrc),                      \
      (__attribute__((address_space(3))) void*)(ldst), 16, 0, 0)

#define MFMA16(a, b, cacc) __builtin_amdgcn_mfma_f32_16x16x32_bf16(a, b, cacc, 0, 0, 0)

__device__ __forceinline__ unsigned short f2bfu(float f) {
  unsigned u = __float_as_uint(f);
  return (unsigned short)((u + 0x7fffu + ((u >> 16) & 1u)) >> 16);  // RNE
}
__device__ __forceinline__ float bfu2f(unsigned short u) {
  return __uint_as_float(((unsigned)u) << 16);
}

// ---------------------------------------------------------------------------
// K0: convert x + 4 weights to bf16
// ---------------------------------------------------------------------------
__global__ __launch_bounds__(256) void cvt5(const float* __restrict__ x,
                                            const float* __restrict__ wq,
                                            const float* __restrict__ wk,
                                            const float* __restrict__ wv,
                                            const float* __restrict__ wo,
                                            unsigned short* __restrict__ ws) {
  long i = (long)blockIdx.x * 256 + threadIdx.x;
  const float* srcf;
  unsigned short* dst;
  long j;
  if (i < 4194304L)      { srcf = x;  dst = ws + OFF_XB; j = i; }
  else if (i < 5242880L) { srcf = wq; dst = ws + OFF_WQ; j = i - 4194304L; }
  else if (i < 6291456L) { srcf = wk; dst = ws + OFF_WK; j = i - 5242880L; }
  else if (i < 7340032L) { srcf = wv; dst = ws + OFF_WV; j = i - 6291456L; }
  else                   { srcf = wo; dst = ws + OFF_WO; j = i - 7340032L; }
  float4 v = ((const float4*)srcf)[j];
  ushort4 o;
  o.x = f2bfu(v.x); o.y = f2bfu(v.y); o.z = f2bfu(v.z); o.w = f2bfu(v.w);
  ((ushort4*)dst)[j] = o;
}

// ---------------------------------------------------------------------------
// 256x256 8-phase BT-GEMM mainloop (unchanged from round 3; see comments there)
// ---------------------------------------------------------------------------
__device__ __forceinline__ void stage_half(const unsigned short* __restrict__ g,
                                           int Kdim, int rowBase, int k0,
                                           unsigned short* lds, int w, int l) {
#pragma unroll
  for (int rr = 0; rr < 2; rr++) {
    int seg = w + rr * 8;
    int row = seg * 8 + (l >> 3);
    int ccol = ((l & 7) ^ (l >> 3)) * 8;
    GLOAD_LDS16(g + (size_t)(rowBase + row) * Kdim + k0 + ccol, lds + seg * 512);
  }
}

__device__ __forceinline__ bf16x8 lds_frag(const unsigned short* half_, int row,
                                           int s, int g) {
  return *(const bf16x8*)((const char*)half_ + row * 128 +
                          ((s * 64 + g * 16) ^ ((row & 7) << 4)));
}

__device__ __forceinline__ void gemm256(const unsigned short* __restrict__ A,
                                        const unsigned short* __restrict__ Bt,
                                        int rowBase, int colBase, int Kdim,
                                        unsigned short* smem, f32x4 (&acc)[8][4]) {
  const int tid = threadIdx.x, w = tid >> 6, l = tid & 63;
  const int wm = w >> 2, wn = w & 3, c = l & 15, g = l >> 4;
  unsigned short* As = smem;
  unsigned short* Bs = smem + 32768;
  const int NT = Kdim / 64;

#pragma unroll
  for (int i = 0; i < 8; i++)
#pragma unroll
    for (int j = 0; j < 4; j++) acc[i][j] = (f32x4){0.f, 0.f, 0.f, 0.f};

  stage_half(A,  Kdim, rowBase,       0,  As + 0 * 8192, w, l);
  stage_half(Bt, Kdim, colBase,       0,  Bs + 0 * 8192, w, l);
  stage_half(Bt, Kdim, colBase + 128, 0,  Bs + 1 * 8192, w, l);
  stage_half(A,  Kdim, rowBase + 128, 0,  As + 1 * 8192, w, l);
  stage_half(A,  Kdim, rowBase,       64, As + 2 * 8192, w, l);
  stage_half(Bt, Kdim, colBase,       64, Bs + 2 * 8192, w, l);
  stage_half(Bt, Kdim, colBase + 128, 64, Bs + 3 * 8192, w, l);
  asm volatile("s_waitcnt vmcnt(6)" ::: "memory");
  asm volatile("s_barrier" ::: "memory");

  bf16x8 aF[4][2], bF[4][2];

  for (int t = 0; t < NT; ++t) {
    const int par = t & 1;
    const unsigned short* A0h = As + (par * 2 + 0) * 8192;
    const unsigned short* A1h = As + (par * 2 + 1) * 8192;
    const unsigned short* B0h = Bs + (par * 2 + 0) * 8192;
    const unsigned short* B1h = Bs + (par * 2 + 1) * 8192;

    // ---- phase 0
#pragma unroll
    for (int m = 0; m < 4; m++) {
      int row = m * 32 + wm * 16 + c;
#pragma unroll
      for (int s = 0; s < 2; s++) aF[m][s] = lds_frag(A0h, row, s, g);
    }
#pragma unroll
    for (int n = 0; n < 2; n++) {
      int row = n * 64 + wn * 16 + c;
#pragma unroll
      for (int s = 0; s < 2; s++) bF[n][s] = lds_frag(B0h, row, s, g);
    }
    if (t + 1 < NT)
      stage_half(A, Kdim, rowBase + 128, (t + 1) * 64,
                 As + (((t + 1) & 1) * 2 + 1) * 8192, w, l);
    asm volatile("s_barrier" ::: "memory");
    __builtin_amdgcn_s_setprio(1);
#pragma unroll
    for (int m = 0; m < 4; m++)
#pragma unroll
      for (int n = 0; n < 2; n++)
#pragma unroll
        for (int s = 0; s < 2; s++) acc[m][n] = MFMA16(aF[m][s], bF[n][s], acc[m][n]);
    __builtin_amdgcn_s_setprio(0);
    asm volatile("s_barrier" ::: "memory");

    // ---- phase 1
#pragma unroll
    for (int n = 0; n < 2; n++) {
      int row = n * 64 + wn * 16 + c;
#pragma unroll
      for (int s = 0; s < 2; s++) bF[2 + n][s] = lds_frag(B1h, row, s, g);
    }
    if (t + 2 < NT)
      stage_half(A, Kdim, rowBase, (t + 2) * 64, As + (par * 2 + 0) * 8192, w, l);
    asm volatile("s_barrier" ::: "memory");
    __builtin_amdgcn_s_setprio(1);
#pragma unroll
    for (int m = 0; m < 4; m++)
#pragma unroll
      for (int n = 0; n < 2; n++)
#pragma unroll
        for (int s = 0; s < 2; s++)
          acc[m][2 + n] = MFMA16(aF[m][s], bF[2 + n][s], acc[m][2 + n]);
    __builtin_amdgcn_s_setprio(0);
    asm volatile("s_barrier" ::: "memory");

    // ---- phase 2
#pragma unroll
    for (int m = 0; m < 4; m++) {
      int row = m * 32 + wm * 16 + c;
#pragma unroll
      for (int s = 0; s < 2; s++) aF[m][s] = lds_frag(A1h, row, s, g);
    }
    if (t + 2 < NT)
      stage_half(Bt, Kdim, colBase, (t + 2) * 64, Bs + (par * 2 + 0) * 8192, w, l);
    asm volatile("s_barrier" ::: "memory");
    __builtin_amdgcn_s_setprio(1);
#pragma unroll
    for (int m = 0; m < 4; m++)
#pragma unroll
      for (int n = 0; n < 2; n++)
#pragma unroll
        for (int s = 0; s < 2; s++)
          acc[4 + m][2 + n] = MFMA16(aF[m][s], bF[2 + n][s], acc[4 + m][2 + n]);
    __builtin_amdgcn_s_setprio(0);
    asm volatile("s_barrier" ::: "memory");

    // ---- phase 3
    if (t + 2 < NT)
      stage_half(Bt, Kdim, colBase + 128, (t + 2) * 64, Bs + (par * 2 + 1) * 8192, w, l);
    asm volatile("s_barrier" ::: "memory");
    __builtin_amdgcn_s_setprio(1);
#pragma unroll
    for (int m = 0; m < 4; m++)
#pragma unroll
      for (int n = 0; n < 2; n++)
#pragma unroll
        for (int s = 0; s < 2; s++)
          acc[4 + m][n] = MFMA16(aF[m][s], bF[n][s], acc[4 + m][n]);
    __builtin_amdgcn_s_setprio(0);
    if (t == NT - 2) asm volatile("s_waitcnt vmcnt(0)" ::: "memory");
    else             asm volatile("s_waitcnt vmcnt(6)" ::: "memory");
    asm volatile("s_barrier" ::: "memory");
  }
}

// ---------------------------------------------------------------------------
// K1: QKV projection.  grid (32 tile_m, 8 tile_n, 3 mat), 512 threads.
// Q scale folds log2(e) so attn softmax uses exp2 directly.
// ---------------------------------------------------------------------------
__global__ __launch_bounds__(512, 2) void qkv_gemm(const unsigned short* __restrict__ xb,
                                                   const unsigned short* __restrict__ wqb,
                                                   const unsigned short* __restrict__ wkb,
                                                   const unsigned short* __restrict__ wvb,
                                                   unsigned short* __restrict__ Qb,
                                                   unsigned short* __restrict__ Kb,
                                                   unsigned short* __restrict__ Vtb) {
  __shared__ __align__(16) unsigned short smem[65536];  // 128 KiB
  const int tid = threadIdx.x, w = tid >> 6, l = tid & 63;
  const int wm = w >> 2, wn = w & 3, c = l & 15, g = l >> 4;
  const int mat = blockIdx.z;
  const unsigned short* Bt = (mat == 0) ? wqb : (mat == 1) ? wkb : wvb;
  const int rowBase = blockIdx.x * 256, colBase = blockIdx.y * 256;

  f32x4 acc[8][4];
  gemm256(xb, Bt, rowBase, colBase, D_, smem, acc);

  const int b = rowBase / S_;
  const int sBase = rowBase & (S_ - 1);

  if (mat < 2) {
    unsigned short* dstb = (mat == 0 ? Qb : Kb);
    const float scale = (mat == 0) ? 0.08838834764831845f * 1.4426950408889634f : 1.0f;
#pragma unroll
    for (int mk = 0; mk < 8; mk++)
#pragma unroll
      for (int nk = 0; nk < 4; nk++) {
        int colT = nk * 64 + wn * 16 + c;
        size_t head = (size_t)(b * H_ + blockIdx.y * 2 + (colT >> 7));
        int hd = colT & 127;
        unsigned short* dst = dstb + head * S_ * HD_;
#pragma unroll
        for (int r = 0; r < 4; r++) {
          int s = sBase + mk * 32 + wm * 16 + g * 4 + r;
          dst[(size_t)s * HD_ + hd] = f2bfu(acc[mk][nk][r] * scale);
        }
      }
  } else {
#pragma unroll
    for (int mk = 0; mk < 8; mk++)
#pragma unroll
      for (int nk = 0; nk < 4; nk++) {
        int colT = nk * 64 + wn * 16 + c;
        size_t head = (size_t)(b * H_ + blockIdx.y * 2 + (colT >> 7));
        int hd = colT & 127;
        int s0 = sBase + mk * 32 + wm * 16 + g * 4;
        ushort4 o;
        o.x = f2bfu(acc[mk][nk][0]); o.y = f2bfu(acc[mk][nk][1]);
        o.z = f2bfu(acc[mk][nk][2]); o.w = f2bfu(acc[mk][nk][3]);
        *(ushort4*)&Vtb[(head * HD_ + hd) * S_ + s0] = o;
      }
  }
}

// ---------------------------------------------------------------------------
// K2: causal flash attention.  Work-balanced: grid (8, 64), 512 blocks
// (= exactly 2 blocks/CU); block i handles q-tiles {15-i, i} -> 34 K-tiles
// each.  Softmax in exp2 domain (Q carries log2e); T13 defer-max (THR=11
// log2-units -> P <= 2048, bf16-safe).
// ---------------------------------------------------------------------------
__global__ __launch_bounds__(512, 4) void attn(const unsigned short* __restrict__ Qb,
                                               const unsigned short* __restrict__ Kb,
                                               const unsigned short* __restrict__ Vtb,
                                               unsigned short* __restrict__ atb) {
  const int bh = blockIdx.y;
  const int tid = threadIdx.x, w = tid >> 6, l = tid & 63;
  const int c = l & 15, g = l >> 4;

  __shared__ __align__(16) unsigned short Ks[2][64 * 128];
  __shared__ __align__(16) unsigned short Vs[2][128 * 64];
  __shared__ __align__(16) unsigned short Ps[8][16 * 64];

  const unsigned short* Qh = Qb  + (size_t)bh * S_ * HD_;
  const unsigned short* Kh = Kb  + (size_t)bh * S_ * HD_;
  const unsigned short* Vh = Vtb + (size_t)bh * HD_ * S_;

  auto STAGE = [&](int buf, int kt) {
    const char* Kt = (const char*)(Kh + (size_t)kt * 64 * HD_);
#pragma unroll
    for (int rr = 0; rr < 2; rr++) {
      int seg = rr * 8 + w;
      {
        int row = seg * 4 + (l >> 4);
        int cbs = ((l & 15) * 16) ^ ((row & 7) << 4);
        GLOAD_LDS16(Kt + row * 256 + cbs, (char*)Ks[buf] + seg * 1024);
      }
      {
        int row = seg * 8 + (l >> 3);
        int cbs = ((l & 7) * 16) ^ ((row & 7) << 4);
        GLOAD_LDS16((const char*)Vh + (size_t)row * (S_ * 2) + kt * 128 + cbs,
                    (char*)Vs[buf] + seg * 1024);
      }
    }
  };

  for (int half = 0; half < 2; ++half) {
    const int qt = half ? (int)blockIdx.x : (S_ / 128 - 1) - (int)blockIdx.x;
    const int q0 = qt * 128;
    const int nkt = 2 * qt + 2;

    // Q fragments in registers: row = q0 + w*16 + c
    bf16x8 qf[4];
    {
      int qrow = q0 + w * 16 + c;
#pragma unroll
      for (int kc = 0; kc < 4; kc++)
        qf[kc] = *(const bf16x8*)&Qh[(size_t)qrow * HD_ + kc * 32 + g * 8];
    }

    f32x4 on[8];
#pragma unroll
    for (int n2 = 0; n2 < 8; n2++) on[n2] = (f32x4){0.f, 0.f, 0.f, 0.f};
    float mrow[4] = {-INFINITY, -INFINITY, -INFINITY, -INFINITY};
    float lrow[4] = {0.f, 0.f, 0.f, 0.f};

    STAGE(0, 0);
    __syncthreads();

    int cur = 0;
    for (int kt = 0; kt < nkt; ++kt) {
      if (kt + 1 < nkt) STAGE(cur ^ 1, kt + 1);

      if (kt * 64 <= q0 + w * 16 + 15) {
        f32x4 sc[4];
#pragma unroll
        for (int n = 0; n < 4; n++) sc[n] = (f32x4){0.f, 0.f, 0.f, 0.f};
        const char* KsB = (const char*)Ks[cur];
        __builtin_amdgcn_s_setprio(1);
#pragma unroll
        for (int n = 0; n < 4; n++) {
          int row = n * 16 + c;
#pragma unroll
          for (int kc = 0; kc < 4; kc++) {
            bf16x8 kf = *(const bf16x8*)(KsB + row * 256 +
                                         ((kc * 64 + g * 16) ^ ((row & 7) << 4)));
            sc[n] = MFMA16(qf[kc], kf, sc[n]);
          }
        }
        __builtin_amdgcn_s_setprio(0);

        if (kt * 64 + 63 > q0 + w * 16) {  // diagonal-overlap: causal mask
#pragma unroll
          for (int n = 0; n < 4; n++)
#pragma unroll
            for (int r = 0; r < 4; r++) {
              int kk = kt * 64 + n * 16 + c;
              int qg = q0 + w * 16 + g * 4 + r;
              if (kk > qg) sc[n][r] = -INFINITY;
            }
        }

        // online softmax (exp2 domain); T13 defer-max with THR=11
        float mt[4];
#pragma unroll
        for (int r = 0; r < 4; r++) {
          mt[r] = fmaxf(fmaxf(sc[0][r], sc[1][r]), fmaxf(sc[2][r], sc[3][r]));
#pragma unroll
          for (int d = 1; d < 16; d <<= 1) mt[r] = fmaxf(mt[r], __shfl_xor(mt[r], d));
        }
        bool need = (mt[0] > mrow[0] + 11.f) || (mt[1] > mrow[1] + 11.f) ||
                    (mt[2] > mrow[2] + 11.f) || (mt[3] > mrow[3] + 11.f);
        if (__any(need)) {
#pragma unroll
          for (int r = 0; r < 4; r++) {
            float mn   = fmaxf(mrow[r], mt[r]);
            float corr = exp2f(mrow[r] - mn);
            mrow[r] = mn;
            lrow[r] *= corr;
#pragma unroll
            for (int n2 = 0; n2 < 8; n2++) on[n2][r] *= corr;
          }
        }
        float rs[4] = {0.f, 0.f, 0.f, 0.f};
#pragma unroll
        for (int n = 0; n < 4; n++)
#pragma unroll
          for (int r = 0; r < 4; r++) {
            float p = exp2f(sc[n][r] - mrow[r]);
            unsigned short u = f2bfu(p);
            rs[r] += bfu2f(u);
            int prow = g * 4 + r;
            int cbyte = ((n * 16 + c) * 2) ^ ((prow & 7) << 4);
            *(unsigned short*)((char*)Ps[w] + prow * 128 + cbyte) = u;
          }
#pragma unroll
        for (int r = 0; r < 4; r++) {
#pragma unroll
          for (int d = 1; d < 16; d <<= 1) rs[r] += __shfl_xor(rs[r], d);
          lrow[r] += rs[r];
        }

        // PV: out[16,128] += P[16,64] * Vt[128,64]^T  (wave-local P)
        const char* VsB = (const char*)Vs[cur];
#pragma unroll
        for (int s = 0; s < 2; s++) {
          bf16x8 pa = *(const bf16x8*)((const char*)Ps[w] + c * 128 +
                                       ((s * 64 + g * 16) ^ ((c & 7) << 4)));
          __builtin_amdgcn_s_setprio(1);
#pragma unroll
          for (int n2 = 0; n2 < 8; n2++) {
            int vrow = n2 * 16 + c;
            bf16x8 vb = *(const bf16x8*)(VsB + vrow * 128 +
                                         ((s * 64 + g * 16) ^ ((vrow & 7) << 4)));
            on[n2] = MFMA16(pa, vb, on[n2]);
          }
          __builtin_amdgcn_s_setprio(0);
        }
      }

      __syncthreads();  // drains prefetch + protects buffers
      cur ^= 1;
    }

    // epilogue: normalize and write attn out [B,S,D] bf16 (registers only,
    // so no extra barrier needed before next half re-stages LDS)
    const int b = bh >> 4, h = bh & 15;
    float inv[4];
#pragma unroll
    for (int r = 0; r < 4; r++) inv[r] = 1.f / lrow[r];
#pragma unroll
    for (int n2 = 0; n2 < 8; n2++)
#pragma unroll
      for (int r = 0; r < 4; r++) {
        size_t srow = (size_t)(b * S_ + q0 + w * 16 + g * 4 + r);
        atb[srow * D_ + h * HD_ + n2 * 16 + c] = f2bfu(on[n2][r] * inv[r]);
      }
  }
}

// ---------------------------------------------------------------------------
// K3: output projection -> f32.  grid (32 tile_m, 8 tile_n), 512 threads.
// ---------------------------------------------------------------------------
__global__ __launch_bounds__(512, 2) void out_gemm(const unsigned short* __restrict__ atb,
                                                   const unsigned short* __restrict__ wob,
                                                   float* __restrict__ out) {
  __shared__ __align__(16) unsigned short smem[65536];  // 128 KiB
  const int tid = threadIdx.x, w = tid >> 6, l = tid & 63;
  const int wm = w >> 2, wn = w & 3, c = l & 15, g = l >> 4;
  const int rowBase = blockIdx.x * 256, colBase = blockIdx.y * 256;

  f32x4 acc[8][4];
  gemm256(atb, wob, rowBase, colBase, D_, smem, acc);

#pragma unroll
  for (int mk = 0; mk < 8; mk++)
#pragma unroll
    for (int nk = 0; nk < 4; nk++) {
      int col = colBase + nk * 64 + wn * 16 + c;
#pragma unroll
      for (int r = 0; r < 4; r++) {
        int row = rowBase + mk * 32 + wm * 16 + g * 4 + r;
        out[(size_t)row * D_ + col] = acc[mk][nk][r];
      }
    }
}

// ---------------------------------------------------------------------------
extern "C" void kernel_launch(void* const* d_in, const int* in_sizes, int n_in,
                              void* d_out, int out_size, void* d_ws, size_t ws_size,
                              hipStream_t stream) {
  const float* x  = (const float*)d_in[0];
  const float* wq = (const float*)d_in[1];
  const float* wk = (const float*)d_in[2];
  const float* wv = (const float*)d_in[3];
  const float* wo = (const float*)d_in[4];
  unsigned short* ws = (unsigned short*)d_ws;
  float* out = (float*)d_out;

  unsigned short* xb  = ws + OFF_XB;
  unsigned short* wqb = ws + OFF_WQ;
  unsigned short* wkb = ws + OFF_WK;
  unsigned short* wvb = ws + OFF_WV;
  unsigned short* wob = ws + OFF_WO;
  unsigned short* Qb  = ws + OFF_QB;
  unsigned short* Kb  = ws + OFF_KB;
  unsigned short* Vtb = ws + OFF_VT;
  unsigned short* atb = ws + OFF_AT;

  hipLaunchKernelGGL(cvt5, dim3(32768), dim3(256), 0, stream, x, wq, wk, wv, wo, ws);
  hipLaunchKernelGGL(qkv_gemm, dim3(32, 8, 3), dim3(512), 0, stream,
                     xb, wqb, wkb, wvb, Qb, Kb, Vtb);
  hipLaunchKernelGGL(attn, dim3(8, 64), dim3(512), 0, stream, Qb, Kb, Vtb, atb);
  hipLaunchKernelGGL(out_gemm, dim3(32, 8), dim3(512), 0, stream, atb, wob, out);
}